// Round 6
// baseline (837.554 us; speedup 1.0000x reference)
//
#include <hip/hip_runtime.h>
#include <hip/hip_fp16.h>
#include <math.h>

#define NN 50000
#define DD 256
#define KK 64
#define HH 8
#define OO 64
#define EE 1600000
#define LRELU_ALPHA 0.2f
#define HK 512   // H*K
#define NX 640   // padded GEMM1 output cols (512 + 16 scores + pad)
#define N3 80    // padded GEMM3 output cols (64 + 2 scores + pad)
#define NGB1 12500 // node-groups per head phase (4 nodes/block)

typedef __attribute__((ext_vector_type(8))) short short8;
typedef __attribute__((ext_vector_type(4))) float floatx4;
typedef __attribute__((ext_vector_type(4))) unsigned int uintx4;

// split f into bf16 hi + bf16 lo (truncation; residual ~2^-16 relative)
__device__ inline void bsplit(float f, unsigned short& h, unsigned short& l) {
    unsigned u = __float_as_uint(f);
    h = (unsigned short)(u >> 16);
    float fh = __uint_as_float(u & 0xffff0000u);
    l = (unsigned short)(__float_as_uint(f - fh) >> 16);
}

// acc += w * f16(lo/hi of pk) without separate v_cvt: v_fma_mix_f32 reads the
// f16 source directly (op_sel_hi[0]=1 -> src0 is f16; op_sel[0] picks half).
__device__ inline void fmamix2(float& a0, float& a1, unsigned int pk, float w) {
    asm("v_fma_mix_f32 %0, %2, %3, %0 op_sel:[0,0,0] op_sel_hi:[1,0,0]\n\t"
        "v_fma_mix_f32 %1, %2, %3, %1 op_sel:[1,0,0] op_sel_hi:[1,0,0]"
        : "+v"(a0), "+v"(a1)
        : "v"(pk), "v"(w));
}

// ---------------------------------------------------------------- small prep kernels
__global__ void pack_heads_kernel(const float* __restrict__ hw, float* __restrict__ Bp) {
    int t = blockIdx.x * 256 + threadIdx.x;
    if (t >= HH * DD * KK) return;
    int h = t >> 14;
    int r = t & 16383;
    int d = r >> 6;
    int k = r & 63;
    Bp[d * HK + h * KK + k] = hw[t];
}

__global__ void bias_pack_kernel(const float* __restrict__ b, const float* __restrict__ Bp,
                                 float* __restrict__ bc) {
    int c = blockIdx.x * 256 + threadIdx.x;
    if (c >= HK) return;
    float s = 0.f;
    for (int d = 0; d < DD; d++) s += b[d] * Bp[d * HK + c];
    bc[c] = s;
}

__global__ void build_wext_kernel(const float* __restrict__ Wc, const float* __restrict__ heads_a,
                                  unsigned short* __restrict__ Th, unsigned short* __restrict__ Tl) {
    int t = blockIdx.x * 256 + threadIdx.x;   // t over NX*DD
    int col = t >> 8, d = t & 255;
    if (col >= NX) return;
    float v = 0.f;
    if (col < HK) {
        v = Wc[d * HK + col];
    } else if (col < HK + 8) {
        int h = col - HK;
        for (int k = 0; k < 64; k++) v += Wc[d * HK + h * 64 + k] * heads_a[h * 128 + k];
    } else if (col < HK + 16) {
        int h = col - HK - 8;
        for (int k = 0; k < 64; k++) v += Wc[d * HK + h * 64 + k] * heads_a[h * 128 + 64 + k];
    }
    unsigned short hi, lo;
    bsplit(v, hi, lo);
    Th[(size_t)col * DD + d] = hi;
    Tl[(size_t)col * DD + d] = lo;
}

__global__ void bias_ext_kernel(const float* __restrict__ bc, const float* __restrict__ heads_a,
                                float* __restrict__ be) {
    int c = blockIdx.x * 256 + threadIdx.x;
    if (c >= NX) return;
    float v = 0.f;
    if (c < HK) v = bc[c];
    else if (c < HK + 8) {
        int h = c - HK;
        for (int k = 0; k < 64; k++) v += bc[h * 64 + k] * heads_a[h * 128 + k];
    } else if (c < HK + 16) {
        int h = c - HK - 8;
        for (int k = 0; k < 64; k++) v += bc[h * 64 + k] * heads_a[h * 128 + 64 + k];
    }
    be[c] = v;
}

__global__ void build_eext_kernel(const float* __restrict__ eW, const float* __restrict__ ea,
                                  unsigned short* __restrict__ Th, unsigned short* __restrict__ Tl) {
    int t = blockIdx.x * 256 + threadIdx.x;   // t over N3*HK
    int col = t >> 9, k = t & 511;
    if (col >= N3) return;
    float v = 0.f;
    if (col < OO) v = eW[(size_t)k * OO + col];
    else if (col == OO) { for (int j = 0; j < OO; j++) v += eW[(size_t)k * OO + j] * ea[j]; }
    else if (col == OO + 1) { for (int j = 0; j < OO; j++) v += eW[(size_t)k * OO + j] * ea[64 + j]; }
    unsigned short hi, lo;
    bsplit(v, hi, lo);
    Th[(size_t)col * HK + k] = hi;
    Tl[(size_t)col * HK + k] = lo;
}

__global__ void split_x_kernel(const float* __restrict__ x, unsigned short* __restrict__ xh,
                               unsigned short* __restrict__ xl) {
    int t = blockIdx.x * 256 + threadIdx.x;   // t over NN*64 float4s
    if (t >= NN * 64) return;
    float4 v = ((const float4*)x)[t];
    ushort4 vh, vl;
    bsplit(v.x, vh.x, vl.x);
    bsplit(v.y, vh.y, vl.y);
    bsplit(v.z, vh.z, vl.z);
    bsplit(v.w, vh.w, vl.w);
    ((ushort4*)xh)[t] = vh;
    ((ushort4*)xl)[t] = vl;
}

// ---------------------------------------------------------------- fp32 SGEMM (tiny Wc only)
#define GM 128
#define GN 128
#define GKT 16
__global__ __launch_bounds__(256) void sgemm128_kernel(
    const float* __restrict__ A, const float* __restrict__ B,
    const float* __restrict__ bias, float* __restrict__ C,
    int M, int N, int K)
{
    __shared__ float As[GKT][GM + 4];
    __shared__ float Bs[GKT][GN + 4];
    int tid = threadIdx.x;
    int row0 = blockIdx.y * GM, col0 = blockIdx.x * GN;
    int tx = tid & 15, ty = tid >> 4;
    int ar = tid >> 1;
    int ac0 = (tid & 1) * 8;
    float acc[8][8] = {};
    for (int k0 = 0; k0 < K; k0 += GKT) {
#pragma unroll
        for (int i = 0; i < 2; i++) {
            int gr = row0 + ar;
            int gc = k0 + ac0 + i * 4;
            float4 v = make_float4(0.f, 0.f, 0.f, 0.f);
            if (gr < M) v = *(const float4*)&A[(size_t)gr * K + gc];
            As[ac0 + i * 4 + 0][ar] = v.x;
            As[ac0 + i * 4 + 1][ar] = v.y;
            As[ac0 + i * 4 + 2][ar] = v.z;
            As[ac0 + i * 4 + 3][ar] = v.w;
        }
#pragma unroll
        for (int i = 0; i < 2; i++) {
            int idx = tid + i * 256;
            int br = idx >> 5;
            int bc = (idx & 31) * 4;
            float4 v = make_float4(0.f, 0.f, 0.f, 0.f);
            int gc = col0 + bc;
            if (gc < N) v = *(const float4*)&B[(size_t)(k0 + br) * N + gc];
            *(float4*)&Bs[br][bc] = v;
        }
        __syncthreads();
#pragma unroll
        for (int k = 0; k < GKT; k++) {
            float4 a0 = *(const float4*)&As[k][ty * 4];
            float4 a1 = *(const float4*)&As[k][64 + ty * 4];
            float4 b0 = *(const float4*)&Bs[k][tx * 4];
            float4 b1 = *(const float4*)&Bs[k][64 + tx * 4];
            float av[8] = {a0.x, a0.y, a0.z, a0.w, a1.x, a1.y, a1.z, a1.w};
            float bv[8] = {b0.x, b0.y, b0.z, b0.w, b1.x, b1.y, b1.z, b1.w};
#pragma unroll
            for (int i = 0; i < 8; i++)
#pragma unroll
                for (int j = 0; j < 8; j++) acc[i][j] += av[i] * bv[j];
        }
        __syncthreads();
    }
#pragma unroll
    for (int i = 0; i < 8; i++) {
        int gr = row0 + (i < 4 ? ty * 4 + i : 64 + ty * 4 + i - 4);
        if (gr >= M) continue;
#pragma unroll
        for (int j = 0; j < 8; j++) {
            int gc = col0 + (j < 4 ? tx * 4 + j : 64 + tx * 4 + j - 4);
            if (gc >= N) continue;
            float v = acc[i][j];
            if (bias) v += bias[gc];
            C[(size_t)gr * N + gc] = v;
        }
    }
}

// ---------------------------------------------------------------- GEMM1: split-bf16 MFMA
// Software-pipelined: prefetch next K-tile into registers during MFMA.
// OOB A-rows load dummy row 0 (outputs masked in epilogue).
// Round-6: Hh_t head-major [h][n][64] fp16 (128-B row per (node,head)) and
// ssrc_t/sdst_t head-major (coalesced column stores, r2 form).
#define LDA 40  // LDS stride in shorts
__global__ __launch_bounds__(256) void mfma_gemm1_kernel(
    const unsigned short* __restrict__ xh, const unsigned short* __restrict__ xl,
    const unsigned short* __restrict__ BhT, const unsigned short* __restrict__ BlT,
    const float* __restrict__ bias_ext,
    __half* __restrict__ Hh_t, float* __restrict__ ssrc_t, float* __restrict__ sdst_t)
{
    __shared__ unsigned short AhL[128 * LDA];
    __shared__ unsigned short AlL[128 * LDA];
    __shared__ unsigned short BhL[128 * LDA];
    __shared__ unsigned short BlL[128 * LDA];
    int tid = threadIdx.x, widx = tid >> 6, lane = tid & 63;
    int row0 = blockIdx.y * 128, col0 = blockIdx.x * 128;
    int wrow = (widx >> 1) * 64, wcol = (widx & 1) * 64;
    int lrow = lane & 15, lq = lane >> 4;
    int sr = tid >> 1;            // 0..127
    int sc = (tid & 1) * 16;      // 0 or 16 (shorts)
    int gr = row0 + sr;
    size_t abase = (gr < NN) ? (size_t)gr * DD : 0;   // dummy row 0 if OOB (masked later)
    size_t bbase = (size_t)(col0 + sr) * DD;
    floatx4 acc[4][4] = {};
    uint4 pah0, pah1, pal0, pal1, pbh0, pbh1, pbl0, pbl1;
    {
        size_t ab = abase + sc, bb = bbase + sc;
        pah0 = *(const uint4*)&xh[ab];   pah1 = *(const uint4*)&xh[ab + 8];
        pal0 = *(const uint4*)&xl[ab];   pal1 = *(const uint4*)&xl[ab + 8];
        pbh0 = *(const uint4*)&BhT[bb];  pbh1 = *(const uint4*)&BhT[bb + 8];
        pbl0 = *(const uint4*)&BlT[bb];  pbl1 = *(const uint4*)&BlT[bb + 8];
    }
    for (int k0 = 0; k0 < DD; k0 += 32) {
        *(uint4*)&AhL[sr * LDA + sc]     = pah0;
        *(uint4*)&AhL[sr * LDA + sc + 8] = pah1;
        *(uint4*)&AlL[sr * LDA + sc]     = pal0;
        *(uint4*)&AlL[sr * LDA + sc + 8] = pal1;
        *(uint4*)&BhL[sr * LDA + sc]     = pbh0;
        *(uint4*)&BhL[sr * LDA + sc + 8] = pbh1;
        *(uint4*)&BlL[sr * LDA + sc]     = pbl0;
        *(uint4*)&BlL[sr * LDA + sc + 8] = pbl1;
        __syncthreads();
        if (k0 + 32 < DD) {
            size_t ab = abase + k0 + 32 + sc, bb = bbase + k0 + 32 + sc;
            pah0 = *(const uint4*)&xh[ab];   pah1 = *(const uint4*)&xh[ab + 8];
            pal0 = *(const uint4*)&xl[ab];   pal1 = *(const uint4*)&xl[ab + 8];
            pbh0 = *(const uint4*)&BhT[bb];  pbh1 = *(const uint4*)&BhT[bb + 8];
            pbl0 = *(const uint4*)&BlT[bb];  pbl1 = *(const uint4*)&BlT[bb + 8];
        }
        short8 ah[4], al[4], bh[4], bl[4];
#pragma unroll
        for (int mi = 0; mi < 4; mi++) {
            int r = wrow + mi * 16 + lrow;
            ah[mi] = *(const short8*)&AhL[r * LDA + lq * 8];
            al[mi] = *(const short8*)&AlL[r * LDA + lq * 8];
        }
#pragma unroll
        for (int ni = 0; ni < 4; ni++) {
            int c = wcol + ni * 16 + lrow;
            bh[ni] = *(const short8*)&BhL[c * LDA + lq * 8];
            bl[ni] = *(const short8*)&BlL[c * LDA + lq * 8];
        }
#pragma unroll
        for (int mi = 0; mi < 4; mi++)
#pragma unroll
            for (int ni = 0; ni < 4; ni++) {
                acc[mi][ni] = __builtin_amdgcn_mfma_f32_16x16x32_bf16(al[mi], bh[ni], acc[mi][ni], 0, 0, 0);
                acc[mi][ni] = __builtin_amdgcn_mfma_f32_16x16x32_bf16(ah[mi], bl[ni], acc[mi][ni], 0, 0, 0);
                acc[mi][ni] = __builtin_amdgcn_mfma_f32_16x16x32_bf16(ah[mi], bh[ni], acc[mi][ni], 0, 0, 0);
            }
        __syncthreads();
    }
#pragma unroll
    for (int mi = 0; mi < 4; mi++)
#pragma unroll
        for (int ni = 0; ni < 4; ni++)
#pragma unroll
            for (int r = 0; r < 4; r++) {
                int grow = row0 + wrow + mi * 16 + lq * 4 + r;
                int gcol = col0 + wcol + ni * 16 + lrow;
                if (grow < NN && gcol < HK + 16) {
                    float v = acc[mi][ni][r] + bias_ext[gcol];
                    if (gcol < HK)
                        Hh_t[((size_t)(gcol >> 6) * NN + grow) * 64 + (gcol & 63)] = __float2half_rn(v);
                    else if (gcol < HK + 8)
                        ssrc_t[(size_t)(gcol - HK) * NN + grow] = v;
                    else
                        sdst_t[(size_t)(gcol - HK - 8) * NN + grow] = v;
                }
            }
}

// ---------------------------------------------------------------- GEMM3: split-bf16 MFMA
// Software-pipelined like GEMM1. 64-row blocks, 4 waves x 16 rows, K=512.
// h2 output stored as fp16 (halves agg_final gather traffic).
__global__ __launch_bounds__(256) void mfma_gemm3_kernel(
    const unsigned short* __restrict__ hch, const unsigned short* __restrict__ hcl,
    const unsigned short* __restrict__ BhT, const unsigned short* __restrict__ BlT,
    __half* __restrict__ h2, float* __restrict__ s2src, float* __restrict__ s2dst)
{
    __shared__ unsigned short AhL[64 * LDA];
    __shared__ unsigned short AlL[64 * LDA];
    __shared__ unsigned short BhL[N3 * LDA];
    __shared__ unsigned short BlL[N3 * LDA];
    int tid = threadIdx.x, widx = tid >> 6, lane = tid & 63;
    int row0 = blockIdx.x * 64;
    int wrow = widx * 16;
    int lrow = lane & 15, lq = lane >> 4;
    int sr = tid >> 2;            // 0..63
    int sc = (tid & 3) * 8;       // 0,8,16,24
    int gr = row0 + sr;
    size_t abase = (gr < NN) ? (size_t)gr * HK : 0;
    int bidx0 = tid;              // always < 320
    int br0 = bidx0 >> 2, bc0 = (bidx0 & 3) * 8;
    int bidx1 = tid + 256;
    bool b1ok = (bidx1 < N3 * 4);
    int br1 = bidx1 >> 2, bc1 = (bidx1 & 3) * 8;
    floatx4 acc[5] = {};
    uint4 pa0, pa1, pb0h, pb0l, pb1h, pb1l;
    {
        pa0 = *(const uint4*)&hch[abase + sc];
        pa1 = *(const uint4*)&hcl[abase + sc];
        pb0h = *(const uint4*)&BhT[(size_t)br0 * HK + bc0];
        pb0l = *(const uint4*)&BlT[(size_t)br0 * HK + bc0];
        if (b1ok) {
            pb1h = *(const uint4*)&BhT[(size_t)br1 * HK + bc1];
            pb1l = *(const uint4*)&BlT[(size_t)br1 * HK + bc1];
        }
    }
    for (int k0 = 0; k0 < HK; k0 += 32) {
        *(uint4*)&AhL[sr * LDA + sc] = pa0;
        *(uint4*)&AlL[sr * LDA + sc] = pa1;
        *(uint4*)&BhL[br0 * LDA + bc0] = pb0h;
        *(uint4*)&BlL[br0 * LDA + bc0] = pb0l;
        if (b1ok) {
            *(uint4*)&BhL[br1 * LDA + bc1] = pb1h;
            *(uint4*)&BlL[br1 * LDA + bc1] = pb1l;
        }
        __syncthreads();
        if (k0 + 32 < HK) {
            size_t ab = abase + k0 + 32 + sc;
            pa0 = *(const uint4*)&hch[ab];
            pa1 = *(const uint4*)&hcl[ab];
            pb0h = *(const uint4*)&BhT[(size_t)br0 * HK + k0 + 32 + bc0];
            pb0l = *(const uint4*)&BlT[(size_t)br0 * HK + k0 + 32 + bc0];
            if (b1ok) {
                pb1h = *(const uint4*)&BhT[(size_t)br1 * HK + k0 + 32 + bc1];
                pb1l = *(const uint4*)&BlT[(size_t)br1 * HK + k0 + 32 + bc1];
            }
        }
        short8 ah, al, bh[5], bl[5];
        int r = wrow + lrow;
        ah = *(const short8*)&AhL[r * LDA + lq * 8];
        al = *(const short8*)&AlL[r * LDA + lq * 8];
#pragma unroll
        for (int ni = 0; ni < 5; ni++) {
            int c = ni * 16 + lrow;
            bh[ni] = *(const short8*)&BhL[c * LDA + lq * 8];
            bl[ni] = *(const short8*)&BlL[c * LDA + lq * 8];
        }
#pragma unroll
        for (int ni = 0; ni < 5; ni++) {
            acc[ni] = __builtin_amdgcn_mfma_f32_16x16x32_bf16(al, bh[ni], acc[ni], 0, 0, 0);
            acc[ni] = __builtin_amdgcn_mfma_f32_16x16x32_bf16(ah, bl[ni], acc[ni], 0, 0, 0);
            acc[ni] = __builtin_amdgcn_mfma_f32_16x16x32_bf16(ah, bh[ni], acc[ni], 0, 0, 0);
        }
        __syncthreads();
    }
#pragma unroll
    for (int ni = 0; ni < 5; ni++)
#pragma unroll
        for (int r = 0; r < 4; r++) {
            int grow = row0 + wrow + lq * 4 + r;
            int gcol = ni * 16 + lrow;
            if (grow < NN) {
                float v = acc[ni][r];
                if (gcol < OO) h2[(size_t)grow * OO + gcol] = __float2half_rn(v);
                else if (gcol == OO) s2src[grow] = v;
                else if (gcol == OO + 1) s2dst[grow] = v;
            }
        }
}

// ---------------------------------------------------------------- CSR build
__global__ void hist_kernel(const int* __restrict__ dst, int* __restrict__ deg) {
    int t = blockIdx.x * 256 + threadIdx.x;
    if (t < EE) atomicAdd(&deg[dst[t]], 1);
}

__global__ void scan1_kernel(const int* __restrict__ deg, int* __restrict__ part,
                             int* __restrict__ bsum) {
    __shared__ int ws_[4];
    int i = blockIdx.x * 256 + threadIdx.x;
    int lane = threadIdx.x & 63, wv = threadIdx.x >> 6;
    int v = (i < NN) ? deg[i] : 0;
    int x = v;
#pragma unroll
    for (int d = 1; d < 64; d <<= 1) {
        int t = __shfl_up(x, d, 64);
        if (lane >= d) x += t;
    }
    if (lane == 63) ws_[wv] = x;
    __syncthreads();
    int add = 0;
    for (int k = 0; k < wv; k++) add += ws_[k];
    x += add;
    if (i < NN) part[i] = x;
    if (threadIdx.x == 255) bsum[blockIdx.x] = x;
}

__global__ void scan2_kernel(int* __restrict__ bsum, int nb) {
    __shared__ int ws_[4];
    int tid = threadIdx.x;
    int lane = tid & 63, wv = tid >> 6;
    int v = (tid < nb) ? bsum[tid] : 0;
    int x = v;
#pragma unroll
    for (int d = 1; d < 64; d <<= 1) {
        int t = __shfl_up(x, d, 64);
        if (lane >= d) x += t;
    }
    if (lane == 63) ws_[wv] = x;
    __syncthreads();
    int add = 0;
    for (int k = 0; k < wv; k++) add += ws_[k];
    x += add;
    if (tid < nb) bsum[tid] = x;
}

__global__ void scan3_kernel(const int* __restrict__ deg, const int* __restrict__ part,
                             const int* __restrict__ bsum, int* __restrict__ offs,
                             int* __restrict__ cursor) {
    int i = blockIdx.x * 256 + threadIdx.x;
    if (i >= NN) return;
    int carry = blockIdx.x ? bsum[blockIdx.x - 1] : 0;
    int incl = part[i] + carry;
    offs[i + 1] = incl;
    cursor[i] = incl - deg[i];
    if (i == 0) offs[0] = 0;
}

__global__ void scatter_kernel(const int* __restrict__ src, const int* __restrict__ dst,
                               int* __restrict__ cursor, int* __restrict__ ssorted) {
    int t = blockIdx.x * 256 + threadIdx.x;
    if (t < EE) {
        int d = dst[t];
        int pos = atomicAdd(&cursor[d], 1);
        ssorted[pos] = src[t];
    }
}

// ---------------------------------------------------------------- head aggregation
// Round-6: the unexplored quadrant of the r2/r3/r4 ledger -- G=1 phase locality
// (8 head phases over [h][n][64] fp16, 6.4 MB working set -> r2's measured
// 437 MB FETCH) combined with the r4-lean inner loop:
// - score phase: 64 lanes = 64 edges, 1 head (exp chain identical to r2)
// - gather: 8 batched uint4 instructions (8 edges x 8 lanes x 16 B = 128-B row)
//   issued back-to-back from LDS-staged (s,w); fma_mix consumes (no cvt)
// - lane owns 8 features (oct): acc reduce = 3 shuffles over edge-group bits
// - epilogue: 8 lanes x 16 B = contiguous 128-B head-slice store, pack in-reg
// LDS staging kept (r5 showed __shfl serializes the issue loop).
__global__ __launch_bounds__(256) void agg_heads_kernel(
    const __half* __restrict__ Hh_t, const float* __restrict__ ssrc_t,
    const float* __restrict__ sdst_t, const int* __restrict__ offs,
    const int* __restrict__ ssorted,
    unsigned short* __restrict__ hch, unsigned short* __restrict__ hcl)
{
    __shared__ int2 sSW[4][64];
    int wv = threadIdx.x >> 6, lane = threadIdx.x & 63;
    int h = blockIdx.x / NGB1;            // head phase (slow in dispatch order)
    int ng = blockIdx.x - h * NGB1;
    int n = ng * 4 + wv;
    if (n >= NN) return;
    int beg = offs[n], deg = offs[n + 1] - beg;
    int g8 = lane >> 3, oct = lane & 7;   // gather coords: edge-in-group, feature octet
    const __half* Hs = Hh_t + (size_t)h * NN * 64;
    const float* srcs = ssrc_t + (size_t)h * NN;
    float sd = (deg > 0) ? sdst_t[(size_t)h * NN + n] : 0.f;
    float acc[8] = {};
    float den = 0.f;
    for (int c0 = 0; c0 < deg; c0 += 64) {
        int jj = c0 + lane;
        int s = 0;
        float wgt = 0.f;
        if (jj < deg) {
            s = ssorted[beg + jj];
            float sv = srcs[s] + sd;
            float e = (sv >= 0.f) ? sv : LRELU_ALPHA * sv;
            wgt = __expf(e);
        }
        den += wgt;
        sSW[wv][lane] = make_int2(s, __float_as_int(wgt));
        int clen = min(64, deg - c0);
        int nst = (clen + 7) >> 3;        // 8-edge steps (wave-uniform guard)
        uint4 vb[8];
        float wb[8];
        // 1) issue all gathers back-to-back (addresses from LDS burst)
#pragma unroll
        for (int st = 0; st < 8; st++) {
            if (st < nst) {
                int2 t2 = sSW[wv][st * 8 + g8];
                wb[st] = __int_as_float(t2.y);   // 0 for padded slots
                vb[st] = *(const uint4*)&Hs[(size_t)t2.x * 64 + oct * 8];
            }
        }
        // 2) consume
#pragma unroll
        for (int st = 0; st < 8; st++) {
            if (st < nst) {
                fmamix2(acc[0], acc[1], vb[st].x, wb[st]);
                fmamix2(acc[2], acc[3], vb[st].y, wb[st]);
                fmamix2(acc[4], acc[5], vb[st].z, wb[st]);
                fmamix2(acc[6], acc[7], vb[st].w, wb[st]);
            }
        }
    }
    // den: full 64-lane sum (edge lanes)
#pragma unroll
    for (int off = 1; off < 64; off <<= 1) den += __shfl_xor(den, off, 64);
    // acc: combine the 8 edge-groups (lane bits 3,4,5) for fixed oct
#pragma unroll
    for (int f = 0; f < 8; f++) {
        acc[f] += __shfl_xor(acc[f], 8, 64);
        acc[f] += __shfl_xor(acc[f], 16, 64);
        acc[f] += __shfl_xor(acc[f], 32, 64);
    }
    if (g8 == 0) {
        float inv = 1.f / (den + 1e-16f);
        unsigned int phw[4], plw[4];
#pragma unroll
        for (int j = 0; j < 4; j++) {
            float r0 = acc[2 * j] * inv, r1 = acc[2 * j + 1] * inv;
            r0 = (r0 > 0.f) ? r0 : (__expf(r0) - 1.f);
            r1 = (r1 > 0.f) ? r1 : (__expf(r1) - 1.f);
            unsigned short h0, l0, h1, l1;
            bsplit(r0, h0, l0);
            bsplit(r1, h1, l1);
            phw[j] = (unsigned)h0 | ((unsigned)h1 << 16);
            plw[j] = (unsigned)l0 | ((unsigned)l1 << 16);
        }
        size_t o = (size_t)n * HK + h * 64 + oct * 8;
        uintx4 vph, vpl;
        vph.x = phw[0]; vph.y = phw[1]; vph.z = phw[2]; vph.w = phw[3];
        vpl.x = plw[0]; vpl.y = plw[1]; vpl.z = plw[2]; vpl.w = plw[3];
        __builtin_nontemporal_store(vph, (uintx4*)&hch[o]);
        __builtin_nontemporal_store(vpl, (uintx4*)&hcl[o]);
    }
}

// ---------------------------------------------------------------- final layer + softmax
// Known-good r4 form: LDS sSW staging, uint4 gathers, fma_mix consume.
#define APW 4
__global__ __launch_bounds__(256) void agg_final_kernel(
    const __half* __restrict__ h2, const float* __restrict__ s2src,
    const float* __restrict__ s2dst, const int* __restrict__ offs,
    const int* __restrict__ ssorted, float* __restrict__ out)
{
    __shared__ int2 sSW[4][64];
    int wv = threadIdx.x >> 6, lane = threadIdx.x & 63;
    int n = blockIdx.x * 4 + wv;
    if (n >= NN) return;
    int beg = offs[n], deg = offs[n + 1] - beg;
    int g = lane >> 3, q = lane & 7;
    float acc[8] = {};
    float den = 0.f;
    float sd = (deg > 0) ? s2dst[n] : 0.f;
    for (int c0 = 0; c0 < deg; c0 += 64) {
        int jj = c0 + lane;
        int s = 0;
        float wgt = 0.f;
        if (jj < deg) {
            s = ssorted[beg + jj];
            float sv = s2src[s] + sd;
            float e = (sv >= 0.f) ? sv : LRELU_ALPHA * sv;
            wgt = __expf(e);
        }
        den += wgt;
        sSW[wv][lane] = make_int2(s, __float_as_int(wgt));
        int clen = min(64, deg - c0);
        int nst = (clen + 7) >> 3;
        for (int base = 0; base < nst; base += APW) {
            uint4 vb[APW];
            float wb[APW];
#pragma unroll
            for (int p2 = 0; p2 < APW; p2++) {
                int st = base + p2;
                int sj = 0;
                float ww = 0.f;
                if (st < nst) {
                    int2 t2 = sSW[wv][st * 8 + g];
                    sj = t2.x;
                    ww = __int_as_float(t2.y);
                }
                wb[p2] = ww;
                vb[p2] = *(const uint4*)&h2[(size_t)sj * OO + q * 8];
            }
#pragma unroll
            for (int p2 = 0; p2 < APW; p2++) {
                fmamix2(acc[0], acc[1], vb[p2].x, wb[p2]);
                fmamix2(acc[2], acc[3], vb[p2].y, wb[p2]);
                fmamix2(acc[4], acc[5], vb[p2].z, wb[p2]);
                fmamix2(acc[6], acc[7], vb[p2].w, wb[p2]);
            }
        }
    }
#pragma unroll
    for (int off = 32; off; off >>= 1) den += __shfl_xor(den, off, 64);
#pragma unroll
    for (int f = 0; f < 8; f++) {
        acc[f] += __shfl_xor(acc[f], 8, 64);
        acc[f] += __shfl_xor(acc[f], 16, 64);
        acc[f] += __shfl_xor(acc[f], 32, 64);
    }
    float inv = 1.f / (den + 1e-16f);
    float r[8];
#pragma unroll
    for (int f = 0; f < 8; f++) {
        float v = acc[f] * inv;
        r[f] = (v > 0.f) ? v : (__expf(v) - 1.f);
    }
    float mm = r[0];
#pragma unroll
    for (int f = 1; f < 8; f++) mm = fmaxf(mm, r[f]);
#pragma unroll
    for (int off = 1; off < 8; off <<= 1) mm = fmaxf(mm, __shfl_xor(mm, off, 64));
    float p[8], sum = 0.f;
#pragma unroll
    for (int f = 0; f < 8; f++) { p[f] = __expf(r[f] - mm); sum += p[f]; }
#pragma unroll
    for (int off = 1; off < 8; off <<= 1) sum += __shfl_xor(sum, off, 64);
    float is = 1.f / sum;
    if (g == 0) {
        float4 o0 = make_float4(p[0] * is, p[1] * is, p[2] * is, p[3] * is);
        float4 o1 = make_float4(p[4] * is, p[5] * is, p[6] * is, p[7] * is);
        *(float4*)&out[(size_t)n * OO + q * 8] = o0;
        *(float4*)&out[(size_t)n * OO + q * 8 + 4] = o1;
    }
}

// ---------------------------------------------------------------- launch
extern "C" void kernel_launch(void* const* d_in, const int* in_sizes, int n_in,
                              void* d_out, int out_size, void* d_ws, size_t ws_size,
                              hipStream_t stream) {
    const float* x       = (const float*)d_in[0];
    const int*   edges   = (const int*)d_in[1];
    const float* layer_W = (const float*)d_in[2];
    const float* layer_b = (const float*)d_in[3];
    const float* heads_W = (const float*)d_in[4];
    const float* heads_a = (const float*)d_in[5];
    const float* end_W   = (const float*)d_in[6];
    const float* end_a   = (const float*)d_in[7];
    float* out = (float*)d_out;

    const int* src = edges;
    const int* dst = edges + EE;

    char* ws = (char*)d_ws;
    size_t wsp = 0;
    auto alloc = [&](size_t bytes) -> void* {
        void* r = ws + wsp;
        wsp += (bytes + 255) & ~(size_t)255;
        return r;
    };
    __half* Hh_t  = (__half*)alloc((size_t)NN * HK * 2);                // 51.2 MB (fp16, head-major)
    unsigned short* hch = (unsigned short*)alloc((size_t)NN * HK * 2);  // 51.2 MB
    unsigned short* hcl = (unsigned short*)alloc((size_t)NN * HK * 2);  // 51.2 MB
    __half* h2    = (__half*)alloc((size_t)NN * OO * 2);                // 6.4 MB (fp16)
    float* Bp    = (float*)alloc((size_t)DD * HK * 4);
    float* Wc    = (float*)alloc((size_t)DD * HK * 4);
    float* bc    = (float*)alloc((size_t)HK * 4);
    unsigned short* WexthT = (unsigned short*)alloc((size_t)NX * DD * 2);
    unsigned short* WextlT = (unsigned short*)alloc((size_t)NX * DD * 2);
    unsigned short* eexthT = (unsigned short*)alloc((size_t)N3 * HK * 2);
    unsigned short* eextlT = (unsigned short*)alloc((size_t)N3 * HK * 2);
    float* bias_ext = (float*)alloc((size_t)NX * 4);
    float* ssrc_t = (float*)alloc((size_t)HH * NN * 4);   // head-major [h][n]
    float* sdst_t = (float*)alloc((size_t)HH * NN * 4);   // head-major [h][n]
    float* s2src = (float*)alloc((size_t)NN * 4);
    float* s2dst = (float*)alloc((size_t)NN * 4);
    int* deg     = (int*)alloc((size_t)NN * 4);
    int* offs    = (int*)alloc((size_t)(NN + 1) * 4);
    int* cursor  = (int*)alloc((size_t)NN * 4);
    int* part    = (int*)alloc((size_t)NN * 4);
    int* bsum    = (int*)alloc((size_t)256 * 4);
    int* ssorted = (int*)alloc((size_t)EE * 4);

    // xh/xl alias hch/hcl: x-splits dead before agg_heads writes hch/hcl
    unsigned short* xh = hch;   // needs NN*DD*2 = 25.6 MB < 51.2 MB
    unsigned short* xl = hcl;

    const int NB = (NN + 255) / 256;   // 196 scan blocks

    (void)hipMemsetAsync(deg, 0, (size_t)NN * 4, stream);

    // weight prep
    pack_heads_kernel<<<(HH * DD * KK + 255) / 256, 256, 0, stream>>>(heads_W, Bp);
    bias_pack_kernel<<<2, 256, 0, stream>>>(layer_b, Bp, bc);
    sgemm128_kernel<<<dim3(HK / GN, DD / GM), 256, 0, stream>>>(
        layer_W, Bp, nullptr, Wc, DD, HK, DD);
    build_wext_kernel<<<(NX * DD + 255) / 256, 256, 0, stream>>>(Wc, heads_a, WexthT, WextlT);
    bias_ext_kernel<<<(NX + 255) / 256, 256, 0, stream>>>(bc, heads_a, bias_ext);
    build_eext_kernel<<<(N3 * HK + 255) / 256, 256, 0, stream>>>(end_W, end_a, eexthT, eextlT);
    split_x_kernel<<<(NN * 64 + 255) / 256, 256, 0, stream>>>(x, xh, xl);

    // GEMM1: Hh_t (head-major, fp16) + ssrc_t/sdst_t fused score columns
    mfma_gemm1_kernel<<<dim3(NX / 128, (NN + 127) / 128), 256, 0, stream>>>(
        xh, xl, WexthT, WextlT, bias_ext, Hh_t, ssrc_t, sdst_t);

    // CSR build
    hist_kernel<<<(EE + 255) / 256, 256, 0, stream>>>(dst, deg);
    scan1_kernel<<<NB, 256, 0, stream>>>(deg, part, bsum);
    scan2_kernel<<<1, 256, 0, stream>>>(bsum, NB);
    scan3_kernel<<<NB, 256, 0, stream>>>(deg, part, bsum, offs, cursor);
    scatter_kernel<<<(EE + 255) / 256, 256, 0, stream>>>(src, dst, cursor, ssorted);

    // per-(node,head) attention aggregation, 8 head phases (hg slow in dispatch)
    agg_heads_kernel<<<8 * NGB1, 256, 0, stream>>>(
        Hh_t, ssrc_t, sdst_t, offs, ssorted, hch, hcl);

    // GEMM3: h2 (fp16) + s2src/s2dst fused score columns
    mfma_gemm3_kernel<<<(NN + 63) / 64, 256, 0, stream>>>(
        hch, hcl, eexthT, eextlT, h2, s2src, s2dst);

    // final aggregation + elu + row softmax
    agg_final_kernel<<<(NN + 3) / 4, 256, 0, stream>>>(h2, s2src, s2dst, offs, ssorted, out);
}

// Round 7
// 772.228 us; speedup vs baseline: 1.0846x; 1.0846x over previous
//
#include <hip/hip_runtime.h>
#include <hip/hip_fp16.h>
#include <math.h>

#define NN 50000
#define DD 256
#define KK 64
#define HH 8
#define OO 64
#define EE 1600000
#define LRELU_ALPHA 0.2f
#define HK 512   // H*K
#define NX 640   // padded GEMM1 output cols (512 + 16 scores + pad)
#define N3 80    // padded GEMM3 output cols (64 + 2 scores + pad)

typedef __attribute__((ext_vector_type(8))) short short8;
typedef __attribute__((ext_vector_type(4))) float floatx4;

// split f into bf16 hi + bf16 lo (truncation; residual ~2^-16 relative)
__device__ inline void bsplit(float f, unsigned short& h, unsigned short& l) {
    unsigned u = __float_as_uint(f);
    h = (unsigned short)(u >> 16);
    float fh = __uint_as_float(u & 0xffff0000u);
    l = (unsigned short)(__float_as_uint(f - fh) >> 16);
}

// ---------------------------------------------------------------- small prep kernels
__global__ void pack_heads_kernel(const float* __restrict__ hw, float* __restrict__ Bp) {
    int t = blockIdx.x * 256 + threadIdx.x;
    if (t >= HH * DD * KK) return;
    int h = t >> 14;
    int r = t & 16383;
    int d = r >> 6;
    int k = r & 63;
    Bp[d * HK + h * KK + k] = hw[t];
}

__global__ void bias_pack_kernel(const float* __restrict__ b, const float* __restrict__ Bp,
                                 float* __restrict__ bc) {
    int c = blockIdx.x * 256 + threadIdx.x;
    if (c >= HK) return;
    float s = 0.f;
    for (int d = 0; d < DD; d++) s += b[d] * Bp[d * HK + c];
    bc[c] = s;
}

__global__ void build_wext_kernel(const float* __restrict__ Wc, const float* __restrict__ heads_a,
                                  unsigned short* __restrict__ Th, unsigned short* __restrict__ Tl) {
    int t = blockIdx.x * 256 + threadIdx.x;   // t over NX*DD
    int col = t >> 8, d = t & 255;
    if (col >= NX) return;
    float v = 0.f;
    if (col < HK) {
        v = Wc[d * HK + col];
    } else if (col < HK + 8) {
        int h = col - HK;
        for (int k = 0; k < 64; k++) v += Wc[d * HK + h * 64 + k] * heads_a[h * 128 + k];
    } else if (col < HK + 16) {
        int h = col - HK - 8;
        for (int k = 0; k < 64; k++) v += Wc[d * HK + h * 64 + k] * heads_a[h * 128 + 64 + k];
    }
    unsigned short hi, lo;
    bsplit(v, hi, lo);
    Th[(size_t)col * DD + d] = hi;
    Tl[(size_t)col * DD + d] = lo;
}

__global__ void bias_ext_kernel(const float* __restrict__ bc, const float* __restrict__ heads_a,
                                float* __restrict__ be) {
    int c = blockIdx.x * 256 + threadIdx.x;
    if (c >= NX) return;
    float v = 0.f;
    if (c < HK) v = bc[c];
    else if (c < HK + 8) {
        int h = c - HK;
        for (int k = 0; k < 64; k++) v += bc[h * 64 + k] * heads_a[h * 128 + k];
    } else if (c < HK + 16) {
        int h = c - HK - 8;
        for (int k = 0; k < 64; k++) v += bc[h * 64 + k] * heads_a[h * 128 + 64 + k];
    }
    be[c] = v;
}

__global__ void build_eext_kernel(const float* __restrict__ eW, const float* __restrict__ ea,
                                  unsigned short* __restrict__ Th, unsigned short* __restrict__ Tl) {
    int t = blockIdx.x * 256 + threadIdx.x;   // t over N3*HK
    int col = t >> 9, k = t & 511;
    if (col >= N3) return;
    float v = 0.f;
    if (col < OO) v = eW[(size_t)k * OO + col];
    else if (col == OO) { for (int j = 0; j < OO; j++) v += eW[(size_t)k * OO + j] * ea[j]; }
    else if (col == OO + 1) { for (int j = 0; j < OO; j++) v += eW[(size_t)k * OO + j] * ea[64 + j]; }
    unsigned short hi, lo;
    bsplit(v, hi, lo);
    Th[(size_t)col * HK + k] = hi;
    Tl[(size_t)col * HK + k] = lo;
}

__global__ void split_x_kernel(const float* __restrict__ x, unsigned short* __restrict__ xh,
                               unsigned short* __restrict__ xl) {
    int t = blockIdx.x * 256 + threadIdx.x;   // t over NN*64 float4s
    if (t >= NN * 64) return;
    float4 v = ((const float4*)x)[t];
    ushort4 vh, vl;
    bsplit(v.x, vh.x, vl.x);
    bsplit(v.y, vh.y, vl.y);
    bsplit(v.z, vh.z, vl.z);
    bsplit(v.w, vh.w, vl.w);
    ((ushort4*)xh)[t] = vh;
    ((ushort4*)xl)[t] = vl;
}

// ---------------------------------------------------------------- fp32 SGEMM (tiny Wc only)
#define GM 128
#define GN 128
#define GKT 16
__global__ __launch_bounds__(256) void sgemm128_kernel(
    const float* __restrict__ A, const float* __restrict__ B,
    const float* __restrict__ bias, float* __restrict__ C,
    int M, int N, int K)
{
    __shared__ float As[GKT][GM + 4];
    __shared__ float Bs[GKT][GN + 4];
    int tid = threadIdx.x;
    int row0 = blockIdx.y * GM, col0 = blockIdx.x * GN;
    int tx = tid & 15, ty = tid >> 4;
    int ar = tid >> 1;
    int ac0 = (tid & 1) * 8;
    float acc[8][8] = {};
    for (int k0 = 0; k0 < K; k0 += GKT) {
#pragma unroll
        for (int i = 0; i < 2; i++) {
            int gr = row0 + ar;
            int gc = k0 + ac0 + i * 4;
            float4 v = make_float4(0.f, 0.f, 0.f, 0.f);
            if (gr < M) v = *(const float4*)&A[(size_t)gr * K + gc];
            As[ac0 + i * 4 + 0][ar] = v.x;
            As[ac0 + i * 4 + 1][ar] = v.y;
            As[ac0 + i * 4 + 2][ar] = v.z;
            As[ac0 + i * 4 + 3][ar] = v.w;
        }
#pragma unroll
        for (int i = 0; i < 2; i++) {
            int idx = tid + i * 256;
            int br = idx >> 5;
            int bc = (idx & 31) * 4;
            float4 v = make_float4(0.f, 0.f, 0.f, 0.f);
            int gc = col0 + bc;
            if (gc < N) v = *(const float4*)&B[(size_t)(k0 + br) * N + gc];
            *(float4*)&Bs[br][bc] = v;
        }
        __syncthreads();
#pragma unroll
        for (int k = 0; k < GKT; k++) {
            float4 a0 = *(const float4*)&As[k][ty * 4];
            float4 a1 = *(const float4*)&As[k][64 + ty * 4];
            float4 b0 = *(const float4*)&Bs[k][tx * 4];
            float4 b1 = *(const float4*)&Bs[k][64 + tx * 4];
            float av[8] = {a0.x, a0.y, a0.z, a0.w, a1.x, a1.y, a1.z, a1.w};
            float bv[8] = {b0.x, b0.y, b0.z, b0.w, b1.x, b1.y, b1.z, b1.w};
#pragma unroll
            for (int i = 0; i < 8; i++)
#pragma unroll
                for (int j = 0; j < 8; j++) acc[i][j] += av[i] * bv[j];
        }
        __syncthreads();
    }
#pragma unroll
    for (int i = 0; i < 8; i++) {
        int gr = row0 + (i < 4 ? ty * 4 + i : 64 + ty * 4 + i - 4);
        if (gr >= M) continue;
#pragma unroll
        for (int j = 0; j < 8; j++) {
            int gc = col0 + (j < 4 ? tx * 4 + j : 64 + tx * 4 + j - 4);
            if (gc >= N) continue;
            float v = acc[i][j];
            if (bias) v += bias[gc];
            C[(size_t)gr * N + gc] = v;
        }
    }
}

// ---------------------------------------------------------------- GEMM1: split-bf16 MFMA
// Software-pipelined: prefetch next K-tile into registers during MFMA.
// OOB A-rows load dummy row 0 (outputs masked in epilogue).
// Hh_t output stored as fp16 (one 128-B line per 64-feature row).
#define LDA 40  // LDS stride in shorts
__global__ __launch_bounds__(256) void mfma_gemm1_kernel(
    const unsigned short* __restrict__ xh, const unsigned short* __restrict__ xl,
    const unsigned short* __restrict__ BhT, const unsigned short* __restrict__ BlT,
    const float* __restrict__ bias_ext,
    __half* __restrict__ Hh_t, float* __restrict__ ssrc_t, float* __restrict__ sdst_t)
{
    __shared__ unsigned short AhL[128 * LDA];
    __shared__ unsigned short AlL[128 * LDA];
    __shared__ unsigned short BhL[128 * LDA];
    __shared__ unsigned short BlL[128 * LDA];
    int tid = threadIdx.x, widx = tid >> 6, lane = tid & 63;
    int row0 = blockIdx.y * 128, col0 = blockIdx.x * 128;
    int wrow = (widx >> 1) * 64, wcol = (widx & 1) * 64;
    int lrow = lane & 15, lq = lane >> 4;
    int sr = tid >> 1;            // 0..127
    int sc = (tid & 1) * 16;      // 0 or 16 (shorts)
    int gr = row0 + sr;
    size_t abase = (gr < NN) ? (size_t)gr * DD : 0;   // dummy row 0 if OOB (masked later)
    size_t bbase = (size_t)(col0 + sr) * DD;
    floatx4 acc[4][4] = {};
    uint4 pah0, pah1, pal0, pal1, pbh0, pbh1, pbl0, pbl1;
    {
        size_t ab = abase + sc, bb = bbase + sc;
        pah0 = *(const uint4*)&xh[ab];   pah1 = *(const uint4*)&xh[ab + 8];
        pal0 = *(const uint4*)&xl[ab];   pal1 = *(const uint4*)&xl[ab + 8];
        pbh0 = *(const uint4*)&BhT[bb];  pbh1 = *(const uint4*)&BhT[bb + 8];
        pbl0 = *(const uint4*)&BlT[bb];  pbl1 = *(const uint4*)&BlT[bb + 8];
    }
    for (int k0 = 0; k0 < DD; k0 += 32) {
        *(uint4*)&AhL[sr * LDA + sc]     = pah0;
        *(uint4*)&AhL[sr * LDA + sc + 8] = pah1;
        *(uint4*)&AlL[sr * LDA + sc]     = pal0;
        *(uint4*)&AlL[sr * LDA + sc + 8] = pal1;
        *(uint4*)&BhL[sr * LDA + sc]     = pbh0;
        *(uint4*)&BhL[sr * LDA + sc + 8] = pbh1;
        *(uint4*)&BlL[sr * LDA + sc]     = pbl0;
        *(uint4*)&BlL[sr * LDA + sc + 8] = pbl1;
        __syncthreads();
        if (k0 + 32 < DD) {
            size_t ab = abase + k0 + 32 + sc, bb = bbase + k0 + 32 + sc;
            pah0 = *(const uint4*)&xh[ab];   pah1 = *(const uint4*)&xh[ab + 8];
            pal0 = *(const uint4*)&xl[ab];   pal1 = *(const uint4*)&xl[ab + 8];
            pbh0 = *(const uint4*)&BhT[bb];  pbh1 = *(const uint4*)&BhT[bb + 8];
            pbl0 = *(const uint4*)&BlT[bb];  pbl1 = *(const uint4*)&BlT[bb + 8];
        }
        short8 ah[4], al[4], bh[4], bl[4];
#pragma unroll
        for (int mi = 0; mi < 4; mi++) {
            int r = wrow + mi * 16 + lrow;
            ah[mi] = *(const short8*)&AhL[r * LDA + lq * 8];
            al[mi] = *(const short8*)&AlL[r * LDA + lq * 8];
        }
#pragma unroll
        for (int ni = 0; ni < 4; ni++) {
            int c = wcol + ni * 16 + lrow;
            bh[ni] = *(const short8*)&BhL[c * LDA + lq * 8];
            bl[ni] = *(const short8*)&BlL[c * LDA + lq * 8];
        }
#pragma unroll
        for (int mi = 0; mi < 4; mi++)
#pragma unroll
            for (int ni = 0; ni < 4; ni++) {
                acc[mi][ni] = __builtin_amdgcn_mfma_f32_16x16x32_bf16(al[mi], bh[ni], acc[mi][ni], 0, 0, 0);
                acc[mi][ni] = __builtin_amdgcn_mfma_f32_16x16x32_bf16(ah[mi], bl[ni], acc[mi][ni], 0, 0, 0);
                acc[mi][ni] = __builtin_amdgcn_mfma_f32_16x16x32_bf16(ah[mi], bh[ni], acc[mi][ni], 0, 0, 0);
            }
        __syncthreads();
    }
#pragma unroll
    for (int mi = 0; mi < 4; mi++)
#pragma unroll
        for (int ni = 0; ni < 4; ni++)
#pragma unroll
            for (int r = 0; r < 4; r++) {
                int grow = row0 + wrow + mi * 16 + lq * 4 + r;
                int gcol = col0 + wcol + ni * 16 + lrow;
                if (grow < NN && gcol < HK + 16) {
                    float v = acc[mi][ni][r] + bias_ext[gcol];
                    if (gcol < HK)
                        Hh_t[((size_t)(gcol >> 6) * NN + grow) * 64 + (gcol & 63)] = __float2half_rn(v);
                    else if (gcol < HK + 8)
                        ssrc_t[(size_t)(gcol - HK) * NN + grow] = v;
                    else
                        sdst_t[(size_t)(gcol - HK - 8) * NN + grow] = v;
                }
            }
}

// ---------------------------------------------------------------- GEMM3: split-bf16 MFMA
// Software-pipelined like GEMM1. 64-row blocks, 4 waves x 16 rows, K=512.
// h2 output stored as fp16 (halves agg_final gather traffic).
__global__ __launch_bounds__(256) void mfma_gemm3_kernel(
    const unsigned short* __restrict__ hch, const unsigned short* __restrict__ hcl,
    const unsigned short* __restrict__ BhT, const unsigned short* __restrict__ BlT,
    __half* __restrict__ h2, float* __restrict__ s2src, float* __restrict__ s2dst)
{
    __shared__ unsigned short AhL[64 * LDA];
    __shared__ unsigned short AlL[64 * LDA];
    __shared__ unsigned short BhL[N3 * LDA];
    __shared__ unsigned short BlL[N3 * LDA];
    int tid = threadIdx.x, widx = tid >> 6, lane = tid & 63;
    int row0 = blockIdx.x * 64;
    int wrow = widx * 16;
    int lrow = lane & 15, lq = lane >> 4;
    int sr = tid >> 2;            // 0..63
    int sc = (tid & 3) * 8;       // 0,8,16,24
    int gr = row0 + sr;
    size_t abase = (gr < NN) ? (size_t)gr * HK : 0;
    int bidx0 = tid;              // always < 320
    int br0 = bidx0 >> 2, bc0 = (bidx0 & 3) * 8;
    int bidx1 = tid + 256;
    bool b1ok = (bidx1 < N3 * 4);
    int br1 = bidx1 >> 2, bc1 = (bidx1 & 3) * 8;
    floatx4 acc[5] = {};
    uint4 pa0, pa1, pb0h, pb0l, pb1h, pb1l;
    {
        pa0 = *(const uint4*)&hch[abase + sc];
        pa1 = *(const uint4*)&hcl[abase + sc];
        pb0h = *(const uint4*)&BhT[(size_t)br0 * HK + bc0];
        pb0l = *(const uint4*)&BlT[(size_t)br0 * HK + bc0];
        if (b1ok) {
            pb1h = *(const uint4*)&BhT[(size_t)br1 * HK + bc1];
            pb1l = *(const uint4*)&BlT[(size_t)br1 * HK + bc1];
        }
    }
    for (int k0 = 0; k0 < HK; k0 += 32) {
        *(uint4*)&AhL[sr * LDA + sc] = pa0;
        *(uint4*)&AlL[sr * LDA + sc] = pa1;
        *(uint4*)&BhL[br0 * LDA + bc0] = pb0h;
        *(uint4*)&BlL[br0 * LDA + bc0] = pb0l;
        if (b1ok) {
            *(uint4*)&BhL[br1 * LDA + bc1] = pb1h;
            *(uint4*)&BlL[br1 * LDA + bc1] = pb1l;
        }
        __syncthreads();
        if (k0 + 32 < HK) {
            size_t ab = abase + k0 + 32 + sc;
            pa0 = *(const uint4*)&hch[ab];
            pa1 = *(const uint4*)&hcl[ab];
            pb0h = *(const uint4*)&BhT[(size_t)br0 * HK + k0 + 32 + bc0];
            pb0l = *(const uint4*)&BlT[(size_t)br0 * HK + k0 + 32 + bc0];
            if (b1ok) {
                pb1h = *(const uint4*)&BhT[(size_t)br1 * HK + k0 + 32 + bc1];
                pb1l = *(const uint4*)&BlT[(size_t)br1 * HK + k0 + 32 + bc1];
            }
        }
        short8 ah, al, bh[5], bl[5];
        int r = wrow + lrow;
        ah = *(const short8*)&AhL[r * LDA + lq * 8];
        al = *(const short8*)&AlL[r * LDA + lq * 8];
#pragma unroll
        for (int ni = 0; ni < 5; ni++) {
            int c = ni * 16 + lrow;
            bh[ni] = *(const short8*)&BhL[c * LDA + lq * 8];
            bl[ni] = *(const short8*)&BlL[c * LDA + lq * 8];
        }
#pragma unroll
        for (int ni = 0; ni < 5; ni++) {
            acc[ni] = __builtin_amdgcn_mfma_f32_16x16x32_bf16(al, bh[ni], acc[ni], 0, 0, 0);
            acc[ni] = __builtin_amdgcn_mfma_f32_16x16x32_bf16(ah, bl[ni], acc[ni], 0, 0, 0);
            acc[ni] = __builtin_amdgcn_mfma_f32_16x16x32_bf16(ah, bh[ni], acc[ni], 0, 0, 0);
        }
        __syncthreads();
    }
#pragma unroll
    for (int ni = 0; ni < 5; ni++)
#pragma unroll
        for (int r = 0; r < 4; r++) {
            int grow = row0 + wrow + lq * 4 + r;
            int gcol = ni * 16 + lrow;
            if (grow < NN) {
                float v = acc[ni][r];
                if (gcol < OO) h2[(size_t)grow * OO + gcol] = __float2half_rn(v);
                else if (gcol == OO) s2src[grow] = v;
                else if (gcol == OO + 1) s2dst[grow] = v;
            }
        }
}

// ---------------------------------------------------------------- CSR build
__global__ void hist_kernel(const int* __restrict__ dst, int* __restrict__ deg) {
    int t = blockIdx.x * 256 + threadIdx.x;
    if (t < EE) atomicAdd(&deg[dst[t]], 1);
}

__global__ void scan1_kernel(const int* __restrict__ deg, int* __restrict__ part,
                             int* __restrict__ bsum) {
    __shared__ int ws_[4];
    int i = blockIdx.x * 256 + threadIdx.x;
    int lane = threadIdx.x & 63, wv = threadIdx.x >> 6;
    int v = (i < NN) ? deg[i] : 0;
    int x = v;
#pragma unroll
    for (int d = 1; d < 64; d <<= 1) {
        int t = __shfl_up(x, d, 64);
        if (lane >= d) x += t;
    }
    if (lane == 63) ws_[wv] = x;
    __syncthreads();
    int add = 0;
    for (int k = 0; k < wv; k++) add += ws_[k];
    x += add;
    if (i < NN) part[i] = x;
    if (threadIdx.x == 255) bsum[blockIdx.x] = x;
}

__global__ void scan2_kernel(int* __restrict__ bsum, int nb) {
    __shared__ int ws_[4];
    int tid = threadIdx.x;
    int lane = tid & 63, wv = tid >> 6;
    int v = (tid < nb) ? bsum[tid] : 0;
    int x = v;
#pragma unroll
    for (int d = 1; d < 64; d <<= 1) {
        int t = __shfl_up(x, d, 64);
        if (lane >= d) x += t;
    }
    if (lane == 63) ws_[wv] = x;
    __syncthreads();
    int add = 0;
    for (int k = 0; k < wv; k++) add += ws_[k];
    x += add;
    if (tid < nb) bsum[tid] = x;
}

__global__ void scan3_kernel(const int* __restrict__ deg, const int* __restrict__ part,
                             const int* __restrict__ bsum, int* __restrict__ offs,
                             int* __restrict__ cursor) {
    int i = blockIdx.x * 256 + threadIdx.x;
    if (i >= NN) return;
    int carry = blockIdx.x ? bsum[blockIdx.x - 1] : 0;
    int incl = part[i] + carry;
    offs[i + 1] = incl;
    cursor[i] = incl - deg[i];
    if (i == 0) offs[0] = 0;
}

__global__ void scatter_kernel(const int* __restrict__ src, const int* __restrict__ dst,
                               int* __restrict__ cursor, int* __restrict__ ssorted) {
    int t = blockIdx.x * 256 + threadIdx.x;
    if (t < EE) {
        int d = dst[t];
        int pos = atomicAdd(&cursor[d], 1);
        ssorted[pos] = src[t];
    }
}

// ---------------------------------------------------------------- head aggregation
// FINAL consolidation: round-1 form, the best measured total (772.9 us).
// One wave per (node, head), head-major grid (8 implicit head phases via
// dispatch order -> 6.4 MB per-phase working set, measured 437 MB FETCH /
// 73% L2 hit). fp16 gather rows (128 B = one L2 line per edge-head). uint2
// loads + __half22float2, AP=8 batches with the st<nst guard (keeps VGPR=36,
// occupancy 72%). Measured: 245 us, VALUBusy 88%.
// Six rounds of restructuring (G=8/G=2 phasing, uint4+fma_mix, shfl overlap,
// vb[8] batching) bracket this kernel at 225-257 us from VALU-bound,
// fetch-bound, and balanced directions -- structural floor for 12.8M random
// 128-B line gathers at the ~4 TB/s measured random-line service rate.
#define AP 8
__global__ __launch_bounds__(256) void agg_heads_kernel(
    const __half* __restrict__ Hh_t, const float* __restrict__ ssrc_t,
    const float* __restrict__ sdst_t, const int* __restrict__ offs,
    const int* __restrict__ ssorted,
    unsigned short* __restrict__ hch, unsigned short* __restrict__ hcl)
{
    __shared__ int2 sSW[4][64];
    int wv = threadIdx.x >> 6, lane = threadIdx.x & 63;
    int w = blockIdx.x * 4 + wv;
    if (w >= NN * HH) return;
    int h = w / NN, n = w - h * NN;
    const __half* Hs = Hh_t + (size_t)h * NN * 64;
    const float* srcs = ssrc_t + (size_t)h * NN;
    int beg = offs[n], deg = offs[n + 1] - beg;
    int g = lane >> 4, q = lane & 15;
    float4 acc = make_float4(0.f, 0.f, 0.f, 0.f);
    float den = 0.f;
    float sd = (deg > 0) ? sdst_t[(size_t)h * NN + n] : 0.f;
    for (int c0 = 0; c0 < deg; c0 += 64) {
        int jj = c0 + lane;
        int s = 0;
        float wgt = 0.f;
        if (jj < deg) {
            s = ssorted[beg + jj];
            float sv = srcs[s] + sd;
            float e = (sv >= 0.f) ? sv : LRELU_ALPHA * sv;
            wgt = __expf(e);
        }
        den += wgt;
        sSW[wv][lane] = make_int2(s, __float_as_int(wgt));
        int clen = min(64, deg - c0);
        int nst = (clen + 3) >> 2;
        for (int base = 0; base < nst; base += AP) {
            uint2 vb[AP];
            float wb[AP];
#pragma unroll
            for (int p2 = 0; p2 < AP; p2++) {
                int st = base + p2;
                int sj = 0;
                float ww = 0.f;
                if (st < nst) {
                    int2 t2 = sSW[wv][st * 4 + g];
                    sj = t2.x;
                    ww = __int_as_float(t2.y);
                }
                wb[p2] = ww;
                vb[p2] = *(const uint2*)&Hs[(size_t)sj * 64 + q * 4];
            }
#pragma unroll
            for (int p2 = 0; p2 < AP; p2++) {
                float2 f01 = __half22float2(*(const __half2*)&vb[p2].x);
                float2 f23 = __half22float2(*(const __half2*)&vb[p2].y);
                acc.x += wb[p2] * f01.x;
                acc.y += wb[p2] * f01.y;
                acc.z += wb[p2] * f23.x;
                acc.w += wb[p2] * f23.y;
            }
        }
    }
#pragma unroll
    for (int off = 32; off; off >>= 1) den += __shfl_xor(den, off, 64);
#pragma unroll
    for (int off = 16; off < 64; off <<= 1) {
        acc.x += __shfl_xor(acc.x, off, 64);
        acc.y += __shfl_xor(acc.y, off, 64);
        acc.z += __shfl_xor(acc.z, off, 64);
        acc.w += __shfl_xor(acc.w, off, 64);
    }
    if (g == 0) {
        float inv = 1.f / (den + 1e-16f);
        float r0 = acc.x * inv, r1 = acc.y * inv, r2 = acc.z * inv, r3 = acc.w * inv;
        r0 = (r0 > 0.f) ? r0 : (__expf(r0) - 1.f);
        r1 = (r1 > 0.f) ? r1 : (__expf(r1) - 1.f);
        r2 = (r2 > 0.f) ? r2 : (__expf(r2) - 1.f);
        r3 = (r3 > 0.f) ? r3 : (__expf(r3) - 1.f);
        ushort4 vh, vl;
        bsplit(r0, vh.x, vl.x);
        bsplit(r1, vh.y, vl.y);
        bsplit(r2, vh.z, vl.z);
        bsplit(r3, vh.w, vl.w);
        size_t o = (size_t)n * HK + h * 64 + q * 4;
        unsigned long long ph =
            (unsigned long long)vh.x | ((unsigned long long)vh.y << 16) |
            ((unsigned long long)vh.z << 32) | ((unsigned long long)vh.w << 48);
        unsigned long long pl =
            (unsigned long long)vl.x | ((unsigned long long)vl.y << 16) |
            ((unsigned long long)vl.z << 32) | ((unsigned long long)vl.w << 48);
        __builtin_nontemporal_store(ph, (unsigned long long*)&hch[o]);
        __builtin_nontemporal_store(pl, (unsigned long long*)&hcl[o]);
    }
}

// ---------------------------------------------------------------- final layer + softmax
// Round-1 form (h2 fp16 gather).
__global__ __launch_bounds__(256) void agg_final_kernel(
    const __half* __restrict__ h2, const float* __restrict__ s2src,
    const float* __restrict__ s2dst, const int* __restrict__ offs,
    const int* __restrict__ ssorted, float* __restrict__ out)
{
    __shared__ int2 sSW[4][64];
    int wv = threadIdx.x >> 6, lane = threadIdx.x & 63;
    int n = blockIdx.x * 4 + wv;
    if (n >= NN) return;
    int beg = offs[n], deg = offs[n + 1] - beg;
    int g = lane >> 4, q = lane & 15;
    float4 acc = make_float4(0.f, 0.f, 0.f, 0.f);
    float den = 0.f;
    float sd = (deg > 0) ? s2dst[n] : 0.f;
    for (int c0 = 0; c0 < deg; c0 += 64) {
        int jj = c0 + lane;
        int s = 0;
        float wgt = 0.f;
        if (jj < deg) {
            s = ssorted[beg + jj];
            float sv = s2src[s] + sd;
            float e = (sv >= 0.f) ? sv : LRELU_ALPHA * sv;
            wgt = __expf(e);
        }
        den += wgt;
        sSW[wv][lane] = make_int2(s, __float_as_int(wgt));
        int clen = min(64, deg - c0);
        int nst = (clen + 3) >> 2;
        for (int base = 0; base < nst; base += AP) {
            uint2 vb[AP];
            float wb[AP];
#pragma unroll
            for (int p2 = 0; p2 < AP; p2++) {
                int st = base + p2;
                int sj = 0;
                float ww = 0.f;
                if (st < nst) {
                    int2 t2 = sSW[wv][st * 4 + g];
                    sj = t2.x;
                    ww = __int_as_float(t2.y);
                }
                wb[p2] = ww;
                vb[p2] = *(const uint2*)&h2[(size_t)sj * OO + q * 4];
            }
#pragma unroll
            for (int p2 = 0; p2 < AP; p2++) {
                float2 f01 = __half22float2(*(const __half2*)&vb[p2].x);
                float2 f23 = __half22float2(*(const __half2*)&vb[p2].y);
                acc.x += wb[p2] * f01.x;
                acc.y += wb[p2] * f01.y;
                acc.z += wb[p2] * f23.x;
                acc.w += wb[p2] * f23.y;
            }
        }
    }
#pragma unroll
    for (int off = 32; off; off >>= 1) den += __shfl_xor(den, off, 64);
#pragma unroll
    for (int off = 16; off < 64; off <<= 1) {
        acc.x += __shfl_xor(acc.x, off, 64);
        acc.y += __shfl_xor(acc.y, off, 64);
        acc.z += __shfl_xor(acc.z, off, 64);
        acc.w += __shfl_xor(acc.w, off, 64);
    }
    float inv = 1.f / (den + 1e-16f);
    float r0 = acc.x * inv, r1 = acc.y * inv, r2 = acc.z * inv, r3 = acc.w * inv;
    r0 = (r0 > 0.f) ? r0 : (__expf(r0) - 1.f);
    r1 = (r1 > 0.f) ? r1 : (__expf(r1) - 1.f);
    r2 = (r2 > 0.f) ? r2 : (__expf(r2) - 1.f);
    r3 = (r3 > 0.f) ? r3 : (__expf(r3) - 1.f);
    float mm = fmaxf(fmaxf(r0, r1), fmaxf(r2, r3));
#pragma unroll
    for (int off = 1; off < 16; off <<= 1) mm = fmaxf(mm, __shfl_xor(mm, off, 64));
    float p0 = __expf(r0 - mm), p1 = __expf(r1 - mm);
    float p2 = __expf(r2 - mm), p3 = __expf(r3 - mm);
    float sum = p0 + p1 + p2 + p3;
#pragma unroll
    for (int off = 1; off < 16; off <<= 1) sum += __shfl_xor(sum, off, 64);
    float is = 1.f / sum;
    if (g == 0) {
        float4 res = make_float4(p0 * is, p1 * is, p2 * is, p3 * is);
        *(float4*)&out[(size_t)n * OO + q * 4] = res;
    }
}

// ---------------------------------------------------------------- launch
extern "C" void kernel_launch(void* const* d_in, const int* in_sizes, int n_in,
                              void* d_out, int out_size, void* d_ws, size_t ws_size,
                              hipStream_t stream) {
    const float* x       = (const float*)d_in[0];
    const int*   edges   = (const int*)d_in[1];
    const float* layer_W = (const float*)d_in[2];
    const float* layer_b = (const float*)d_in[3];
    const float* heads_W = (const float*)d_in[4];
    const float* heads_a = (const float*)d_in[5];
    const float* end_W   = (const float*)d_in[6];
    const float* end_a   = (const float*)d_in[7];
    float* out = (float*)d_out;

    const int* src = edges;
    const int* dst = edges + EE;

    char* ws = (char*)d_ws;
    size_t wsp = 0;
    auto alloc = [&](size_t bytes) -> void* {
        void* r = ws + wsp;
        wsp += (bytes + 255) & ~(size_t)255;
        return r;
    };
    __half* Hh_t  = (__half*)alloc((size_t)NN * HK * 2);                // 51.2 MB (fp16, head-major)
    unsigned short* hch = (unsigned short*)alloc((size_t)NN * HK * 2);  // 51.2 MB
    unsigned short* hcl = (unsigned short*)alloc((size_t)NN * HK * 2);  // 51.2 MB
    __half* h2    = (__half*)alloc((size_t)NN * OO * 2);                // 6.4 MB (fp16)
    float* Bp    = (float*)alloc((size_t)DD * HK * 4);
    float* Wc    = (float*)alloc((size_t)DD * HK * 4);
    float* bc    = (float*)alloc((size_t)HK * 4);
    unsigned short* WexthT = (unsigned short*)alloc((size_t)NX * DD * 2);
    unsigned short* WextlT = (unsigned short*)alloc((size_t)NX * DD * 2);
    unsigned short* eexthT = (unsigned short*)alloc((size_t)N3 * HK * 2);
    unsigned short* eextlT = (unsigned short*)alloc((size_t)N3 * HK * 2);
    float* bias_ext = (float*)alloc((size_t)NX * 4);
    float* ssrc_t = (float*)alloc((size_t)HH * NN * 4);
    float* sdst_t = (float*)alloc((size_t)HH * NN * 4);
    float* s2src = (float*)alloc((size_t)NN * 4);
    float* s2dst = (float*)alloc((size_t)NN * 4);
    int* deg     = (int*)alloc((size_t)NN * 4);
    int* offs    = (int*)alloc((size_t)(NN + 1) * 4);
    int* cursor  = (int*)alloc((size_t)NN * 4);
    int* part    = (int*)alloc((size_t)NN * 4);
    int* bsum    = (int*)alloc((size_t)256 * 4);
    int* ssorted = (int*)alloc((size_t)EE * 4);

    // xh/xl alias hch/hcl: x-splits dead before agg_heads writes hch/hcl
    unsigned short* xh = hch;   // needs NN*DD*2 = 25.6 MB < 51.2 MB
    unsigned short* xl = hcl;

    const int NB = (NN + 255) / 256;   // 196 scan blocks

    (void)hipMemsetAsync(deg, 0, (size_t)NN * 4, stream);

    // weight prep
    pack_heads_kernel<<<(HH * DD * KK + 255) / 256, 256, 0, stream>>>(heads_W, Bp);
    bias_pack_kernel<<<2, 256, 0, stream>>>(layer_b, Bp, bc);
    sgemm128_kernel<<<dim3(HK / GN, DD / GM), 256, 0, stream>>>(
        layer_W, Bp, nullptr, Wc, DD, HK, DD);
    build_wext_kernel<<<(NX * DD + 255) / 256, 256, 0, stream>>>(Wc, heads_a, WexthT, WextlT);
    bias_ext_kernel<<<(NX + 255) / 256, 256, 0, stream>>>(bc, heads_a, bias_ext);
    build_eext_kernel<<<(N3 * HK + 255) / 256, 256, 0, stream>>>(end_W, end_a, eexthT, eextlT);
    split_x_kernel<<<(NN * 64 + 255) / 256, 256, 0, stream>>>(x, xh, xl);

    // GEMM1: Hh_t (head-major, fp16) + ssrc_t/sdst_t fused score columns
    mfma_gemm1_kernel<<<dim3(NX / 128, (NN + 127) / 128), 256, 0, stream>>>(
        xh, xl, WexthT, WextlT, bias_ext, Hh_t, ssrc_t, sdst_t);

    // CSR build
    hist_kernel<<<(EE + 255) / 256, 256, 0, stream>>>(dst, deg);
    scan1_kernel<<<NB, 256, 0, stream>>>(deg, part, bsum);
    scan2_kernel<<<1, 256, 0, stream>>>(bsum, NB);
    scan3_kernel<<<NB, 256, 0, stream>>>(deg, part, bsum, offs, cursor);
    scatter_kernel<<<(EE + 255) / 256, 256, 0, stream>>>(src, dst, cursor, ssorted);

    // per-head attention aggregation -> split-bf16 hcat (overwrites xh/xl region)
    agg_heads_kernel<<<(NN * HH + 3) / 4, 256, 0, stream>>>(
        Hh_t, ssrc_t, sdst_t, offs, ssorted, hch, hcl);

    // GEMM3: h2 (fp16) + s2src/s2dst fused score columns
    mfma_gemm3_kernel<<<(NN + 63) / 64, 256, 0, stream>>>(
        hch, hcl, eexthT, eextlT, h2, s2src, s2dst);

    // final aggregation + elu + row softmax
    agg_final_kernel<<<(NN + 3) / 4, 256, 0, stream>>>(h2, s2src, s2dst, offs, ssorted, out);
}